// Round 2
// baseline (162.867 us; speedup 1.0000x reference)
//
#include <hip/hip_runtime.h>
#include <hip/hip_bf16.h>

#define NB 16
#define NC 256
#define NH 64
#define NW 64

typedef __attribute__((ext_vector_type(8))) short bf16x8;
typedef __attribute__((ext_vector_type(4))) float f32x4;

__device__ __forceinline__ unsigned short f2bf(float f) {
    union { float f; unsigned int u; } v; v.f = f;
    unsigned int u = v.u;
    u += 0x7fffu + ((u >> 16) & 1u);   // round-to-nearest-even
    return (unsigned short)(u >> 16);
}

// swizzled elem index, [rows][256] bf16 tile (row = 512B): 16B-block XOR swizzle
__device__ __forceinline__ int idxT(int row, int col) {
    return row * 256 + ((((col >> 3) ^ (row & 7)) << 3) | (col & 7));
}

__global__ void conv_weights(const float* __restrict__ wq,
                             const float* __restrict__ wk,
                             const float* __restrict__ wv,
                             unsigned short* __restrict__ wsb) {
    int i = blockIdx.x * 256 + threadIdx.x;   // float4 index, 16384 total
    float4 q = ((const float4*)wq)[i];
    float4 k = ((const float4*)wk)[i];
    float4 v = ((const float4*)wv)[i];
    ushort4 uq = { f2bf(q.x), f2bf(q.y), f2bf(q.z), f2bf(q.w) };
    ushort4 uk = { f2bf(k.x), f2bf(k.y), f2bf(k.z), f2bf(k.w) };
    ushort4 uv = { f2bf(v.x), f2bf(v.y), f2bf(v.z), f2bf(v.w) };
    ((ushort4*)wsb)[i] = uq;
    ((ushort4*)(wsb + 65536))[i] = uk;
    ((ushort4*)(wsb + 131072))[i] = uv;
}

// LDS layout (shorts), total 39936 shorts = 78 KiB -> 2 blocks/CU:
//   AT  : [0,16384)       A^T [w=64][c=256], 16B-block XOR swizzle
//   AV  : [16384,34816)   first AL [c=256][w=64]; then Vs [c=256] stride 72
//   QK  : [34816,39936)   Qc [64][40] @34816, Kc [64][40] @37376;
//                         later ATT [64][72] @34816 (aliases Qc+Kc)
#define OFF_AV   16384
#define OFF_QC   34816
#define OFF_KC   37376
#define OFF_ATT  34816
#define VS_STR   72
#define QC_STR   40
#define ATT_STR  72

__launch_bounds__(512, 4)
__global__ void mha_fused(const float* __restrict__ a,
                          const unsigned short* __restrict__ wsb,
                          const float* __restrict__ bq,
                          const float* __restrict__ bk,
                          const float* __restrict__ bv,
                          float* __restrict__ out) {
    __shared__ __align__(16) unsigned short smem[39936];
    unsigned short* AT  = smem;
    unsigned short* AL  = smem + OFF_AV;
    unsigned short* Vs  = smem + OFF_AV;
    unsigned short* Qc  = smem + OFF_QC;
    unsigned short* Kc  = smem + OFF_KC;
    unsigned short* ATT = smem + OFF_ATT;

    const int tid = threadIdx.x;
    const int b = blockIdx.x >> 6;
    const int h = blockIdx.x & 63;
    const float* aB = a + (size_t)b * (NC * NH * NW) + h * NW;

    // ---- stage 1: global (coalesced float4) -> AL[c][w] bf16 ----
    #pragma unroll
    for (int i = 0; i < 8; ++i) {
        int f = tid + i * 512;            // 0..4095 float4s
        int c = f >> 4;
        int w4 = (f & 15) << 2;
        float4 val = *(const float4*)(aB + (size_t)c * (NH * NW) + w4);
        ushort4 u = { f2bf(val.x), f2bf(val.y), f2bf(val.z), f2bf(val.w) };
        *(ushort4*)(AL + c * 64 + w4) = u;
    }
    __syncthreads();

    // ---- stage 1b: LDS transpose AL[c][w] -> AT[w][c] (swizzled) ----
    {
        int w = tid & 63;
        int cg = tid >> 6;
        #pragma unroll
        for (int it = 0; it < 8; ++it) {
            int c0 = cg * 4 + it * 32;
            ushort4 t;
            t.x = AL[(c0 + 0) * 64 + w];
            t.y = AL[(c0 + 1) * 64 + w];
            t.z = AL[(c0 + 2) * 64 + w];
            t.w = AL[(c0 + 3) * 64 + w];
            *(ushort4*)(AT + idxT(w, c0)) = t;
        }
    }
    __syncthreads();

    const int wv_ = tid >> 6;
    const int lane = tid & 63;
    const int l15 = lane & 15;
    const int g = lane >> 4;

    // ---- stage V: Vs = Wv * A   [M=o: 2 tiles/wave, N=x: 4 tiles] ----
    // (overwrites AL, which is dead after the transpose barrier)
    {
        f32x4 acc[2][4];
        #pragma unroll
        for (int mi = 0; mi < 2; ++mi) {
            int m0 = (wv_ * 2 + mi) * 16;
            #pragma unroll
            for (int r = 0; r < 4; ++r) {
                float bvl = bv[m0 + g * 4 + r];
                #pragma unroll
                for (int n = 0; n < 4; ++n) acc[mi][n][r] = bvl;
            }
        }
        #pragma unroll
        for (int kk = 0; kk < 8; ++kk) {
            bf16x8 afw[2], bfa[4];
            #pragma unroll
            for (int mi = 0; mi < 2; ++mi) {
                int m0 = (wv_ * 2 + mi) * 16;
                afw[mi] = *(const bf16x8*)(wsb + 131072 + (m0 + l15) * 256 + kk * 32 + g * 8);
            }
            #pragma unroll
            for (int n = 0; n < 4; ++n) {
                int x = n * 16 + l15;
                bfa[n] = *(const bf16x8*)(AT + x * 256 + (((kk * 4 + g) ^ (x & 7)) << 3));
            }
            #pragma unroll
            for (int mi = 0; mi < 2; ++mi)
                #pragma unroll
                for (int n = 0; n < 4; ++n)
                    acc[mi][n] = __builtin_amdgcn_mfma_f32_16x16x32_bf16(afw[mi], bfa[n], acc[mi][n], 0, 0, 0);
        }
        #pragma unroll
        for (int mi = 0; mi < 2; ++mi)
            #pragma unroll
            for (int n = 0; n < 4; ++n)
                #pragma unroll
                for (int r = 0; r < 4; ++r) {
                    int c = (wv_ * 2 + mi) * 16 + g * 4 + r;
                    int x = n * 16 + l15;
                    Vs[c * VS_STR + x] = f2bf(acc[mi][n][r]);
                }
    }
    // no barrier needed here: Vs region untouched until stage 4 (many barriers between)

    // ---- chunked Q/K projection + attn accumulation over o-chunks of 32 ----
    f32x4 acc3[2] = { { 0, 0, 0, 0 }, { 0, 0, 0, 0 } };
    const int mtq = wv_ & 1;      // o-tile within chunk (0..1)
    const int ntq = wv_ >> 1;     // w-tile (0..3)
    const int mt3 = wv_ >> 1;     // attn: w-tile (0..3)
    const int xb  = (wv_ & 1) * 2; // attn: x-tiles xb, xb+1

    #pragma unroll 1
    for (int ch = 0; ch < 8; ++ch) {
        const int o0 = ch * 32 + mtq * 16;   // global o base for this wave's tile
        f32x4 accq, acck;
        #pragma unroll
        for (int r = 0; r < 4; ++r) {
            accq[r] = bq[o0 + g * 4 + r];
            acck[r] = bk[o0 + g * 4 + r];
        }
        const unsigned short* wqrow = wsb + (o0 + l15) * 256;
        const unsigned short* wkrow = wsb + 65536 + (o0 + l15) * 256;
        const int w = ntq * 16 + l15;
        #pragma unroll
        for (int kk = 0; kk < 8; ++kk) {
            bf16x8 awq = *(const bf16x8*)(wqrow + kk * 32 + g * 8);
            bf16x8 awk = *(const bf16x8*)(wkrow + kk * 32 + g * 8);
            bf16x8 bfa = *(const bf16x8*)(AT + w * 256 + (((kk * 4 + g) ^ (w & 7)) << 3));
            accq = __builtin_amdgcn_mfma_f32_16x16x32_bf16(awq, bfa, accq, 0, 0, 0);
            acck = __builtin_amdgcn_mfma_f32_16x16x32_bf16(awk, bfa, acck, 0, 0, 0);
        }
        // write Qc/Kc [w][o_local]: o_local = mtq*16 + g*4 + r (contiguous r -> b64)
        {
            ushort4 uq = { f2bf(accq[0]), f2bf(accq[1]), f2bf(accq[2]), f2bf(accq[3]) };
            ushort4 uk = { f2bf(acck[0]), f2bf(acck[1]), f2bf(acck[2]), f2bf(acck[3]) };
            *(ushort4*)(Qc + w * QC_STR + mtq * 16 + g * 4) = uq;
            *(ushort4*)(Kc + w * QC_STR + mtq * 16 + g * 4) = uk;
        }
        __syncthreads();
        // attn partial: K=32 (one MFMA per tile), 2 tiles per wave
        {
            const int wr = mt3 * 16 + l15;
            bf16x8 aq = *(const bf16x8*)(Qc + wr * QC_STR + g * 8);
            #pragma unroll
            for (int j = 0; j < 2; ++j) {
                const int xr = (xb + j) * 16 + l15;
                bf16x8 bkf = *(const bf16x8*)(Kc + xr * QC_STR + g * 8);
                acc3[j] = __builtin_amdgcn_mfma_f32_16x16x32_bf16(aq, bkf, acc3[j], 0, 0, 0);
            }
        }
        __syncthreads();   // protect Qc/Kc for next chunk's overwrite
    }

    // ---- write ATT[w][x] (aliases Qc/Kc region; last barrier protects) ----
    #pragma unroll
    for (int j = 0; j < 2; ++j) {
        const int x = (xb + j) * 16 + l15;
        #pragma unroll
        for (int r = 0; r < 4; ++r) {
            const int wrow = mt3 * 16 + g * 4 + r;
            ATT[wrow * ATT_STR + x] = f2bf(acc3[j][r]);
        }
    }
    __syncthreads();

    // ---- stage 4: O = Vs * ATT^T (K = x = 64), fp32 residual epilogue ----
    {
        f32x4 acc[2][4];
        #pragma unroll
        for (int mi = 0; mi < 2; ++mi)
            #pragma unroll
            for (int n = 0; n < 4; ++n)
                acc[mi][n] = { 0.f, 0.f, 0.f, 0.f };
        #pragma unroll
        for (int kk = 0; kk < 2; ++kk) {
            bf16x8 av[2], bt[4];
            #pragma unroll
            for (int mi = 0; mi < 2; ++mi) {
                int c = (wv_ * 2 + mi) * 16 + l15;
                av[mi] = *(const bf16x8*)(Vs + c * VS_STR + kk * 32 + g * 8);
            }
            #pragma unroll
            for (int n = 0; n < 4; ++n) {
                int wrow = n * 16 + l15;
                bt[n] = *(const bf16x8*)(ATT + wrow * ATT_STR + kk * 32 + g * 8);
            }
            #pragma unroll
            for (int mi = 0; mi < 2; ++mi)
                #pragma unroll
                for (int n = 0; n < 4; ++n)
                    acc[mi][n] = __builtin_amdgcn_mfma_f32_16x16x32_bf16(av[mi], bt[n], acc[mi][n], 0, 0, 0);
        }
        #pragma unroll
        for (int mi = 0; mi < 2; ++mi)
            #pragma unroll
            for (int n = 0; n < 4; ++n)
                #pragma unroll
                for (int r = 0; r < 4; ++r) {
                    int c = (wv_ * 2 + mi) * 16 + g * 4 + r;
                    int w = n * 16 + l15;
                    size_t off = (size_t)b * (NC * NH * NW) + (size_t)c * (NH * NW) + h * NW + w;
                    out[off] = a[off] + acc[mi][n][r];
                }
    }
}

extern "C" void kernel_launch(void* const* d_in, const int* in_sizes, int n_in,
                              void* d_out, int out_size, void* d_ws, size_t ws_size,
                              hipStream_t stream) {
    (void)in_sizes; (void)n_in; (void)out_size; (void)ws_size;
    const float* a  = (const float*)d_in[0];
    const float* wq = (const float*)d_in[1];
    const float* bq = (const float*)d_in[2];
    const float* wk = (const float*)d_in[3];
    const float* bk = (const float*)d_in[4];
    const float* wv = (const float*)d_in[5];
    const float* bv = (const float*)d_in[6];
    float* out = (float*)d_out;
    unsigned short* wsb = (unsigned short*)d_ws;  // 3 x 256x256 bf16 weights

    conv_weights<<<dim3(64), dim3(256), 0, stream>>>(wq, wk, wv, wsb);
    mha_fused<<<dim3(NB * NH), dim3(512), 0, stream>>>(a, wsb, bq, bk, bv, out);
}

// Round 3
// 92.560 us; speedup vs baseline: 1.7596x; 1.7596x over previous
//
#include <hip/hip_runtime.h>
#include <hip/hip_bf16.h>

#define NB 16
#define NC 256
#define NH 64
#define NW 64

typedef __attribute__((ext_vector_type(8))) short bf16x8;
typedef __attribute__((ext_vector_type(4))) float f32x4;

__device__ __forceinline__ unsigned short f2bf(float f) {
    union { float f; unsigned int u; } v; v.f = f;
    unsigned int u = v.u;
    u += 0x7fffu + ((u >> 16) & 1u);   // round-to-nearest-even
    return (unsigned short)(u >> 16);
}

__global__ void conv_weights(const float* __restrict__ wq,
                             const float* __restrict__ wk,
                             const float* __restrict__ wv,
                             unsigned short* __restrict__ wsb) {
    int i = blockIdx.x * 256 + threadIdx.x;   // float4 index, 16384 total
    float4 q = ((const float4*)wq)[i];
    float4 k = ((const float4*)wk)[i];
    float4 v = ((const float4*)wv)[i];
    ushort4 uq = { f2bf(q.x), f2bf(q.y), f2bf(q.z), f2bf(q.w) };
    ushort4 uk = { f2bf(k.x), f2bf(k.y), f2bf(k.z), f2bf(k.w) };
    ushort4 uv = { f2bf(v.x), f2bf(v.y), f2bf(v.z), f2bf(v.w) };
    ((ushort4*)wsb)[i] = uq;
    ((ushort4*)(wsb + 65536))[i] = uk;
    ((ushort4*)(wsb + 131072))[i] = uv;
}

// LDS (shorts, 49152 = 96 KiB):
//   AT [64 w][256 c]  @0       (16B-block XOR swizzle by row&7)
//   QT [64 w][256 o]  @16384   -> later Vs [256 c][64 x]
//   KT [64 x][256 o]  @32768   -> later ATT [64 w][64 x]
__launch_bounds__(512, 2)
__global__ void mha_fused(const float* __restrict__ a,
                          const unsigned short* __restrict__ wsb,
                          const float* __restrict__ bq,
                          const float* __restrict__ bk,
                          const float* __restrict__ bv,
                          float* __restrict__ out) {
    __shared__ __align__(16) unsigned short smem[49152];
    unsigned short* AT  = smem;
    unsigned short* QT  = smem + 16384;
    unsigned short* KT  = smem + 32768;
    unsigned short* Vs  = smem + 16384;   // aliases QT (dead after attn)
    unsigned short* ATT = smem + 32768;   // aliases KT (dead after attn)

    const int tid = threadIdx.x;
    const int b = blockIdx.x >> 6;
    const int h = blockIdx.x & 63;
    const float* aB = a + (size_t)b * (NC * NH * NW) + h * NW;

    // ---- stage 1: global [c][w] -> register 4x4 transpose -> AT[w][c] ----
    #pragma unroll
    for (int half = 0; half < 2; ++half) {
        int mt = tid + half * 512;         // micro-tile id, 1024 total
        int c0 = (mt >> 4) << 2;           // 0,4,...,252
        int w0 = (mt & 15) << 2;           // 0,4,...,60
        float4 r0 = *(const float4*)(aB + (size_t)(c0 + 0) * 4096 + w0);
        float4 r1 = *(const float4*)(aB + (size_t)(c0 + 1) * 4096 + w0);
        float4 r2 = *(const float4*)(aB + (size_t)(c0 + 2) * 4096 + w0);
        float4 r3 = *(const float4*)(aB + (size_t)(c0 + 3) * 4096 + w0);
        const float* f0 = (const float*)&r0;
        const float* f1 = (const float*)&r1;
        const float* f2 = (const float*)&r2;
        const float* f3 = (const float*)&r3;
        #pragma unroll
        for (int j = 0; j < 4; ++j) {
            int w = w0 + j;
            ushort4 u = { f2bf(f0[j]), f2bf(f1[j]), f2bf(f2[j]), f2bf(f3[j]) };
            *(ushort4*)(AT + w * 256 + ((((c0 >> 3) ^ (w & 7)) << 3) | (c0 & 7))) = u;
        }
    }
    __syncthreads();

    const int wv_ = tid >> 6;
    const int lane = tid & 63;
    const int l15 = lane & 15;
    const int g = lane >> 4;

    // ---- stage 2a: Q,K proj. A-op = W rows o, B-op = AT rows w.
    //      D[row=o][col=w] -> ushort4 epilogue along o into QT/KT[w][o] ----
    {
        f32x4 acc[4][4];
        const unsigned short* wrow[4];
        #pragma unroll
        for (int j = 0; j < 4; ++j) {
            int strip = wv_ * 4 + j;            // 0..15 Q, 16..31 K
            const float* bias = (strip < 16) ? bq : bk;
            const unsigned short* wb = (strip < 16) ? wsb : (wsb + 65536);
            int o_l = (strip & 15) * 16;
            wrow[j] = wb + (o_l + l15) * 256;
            f32x4 bi = { bias[o_l + g * 4 + 0], bias[o_l + g * 4 + 1],
                         bias[o_l + g * 4 + 2], bias[o_l + g * 4 + 3] };
            #pragma unroll
            for (int m = 0; m < 4; ++m) acc[j][m] = bi;
        }
        #pragma unroll
        for (int kk = 0; kk < 8; ++kk) {
            bf16x8 wf[4], atf[4];
            #pragma unroll
            for (int j = 0; j < 4; ++j)
                wf[j] = *(const bf16x8*)(wrow[j] + kk * 32 + g * 8);
            #pragma unroll
            for (int m = 0; m < 4; ++m) {
                int w = m * 16 + l15;
                atf[m] = *(const bf16x8*)(AT + w * 256 + (((kk * 4 + g) ^ (w & 7)) << 3));
            }
            #pragma unroll
            for (int j = 0; j < 4; ++j)
                #pragma unroll
                for (int m = 0; m < 4; ++m)
                    acc[j][m] = __builtin_amdgcn_mfma_f32_16x16x32_bf16(wf[j], atf[m], acc[j][m], 0, 0, 0);
        }
        #pragma unroll
        for (int j = 0; j < 4; ++j) {
            int strip = wv_ * 4 + j;
            unsigned short* T = (strip < 16) ? QT : KT;
            int o0 = (strip & 15) * 16 + g * 4;
            #pragma unroll
            for (int m = 0; m < 4; ++m) {
                int w = m * 16 + l15;
                ushort4 u = { f2bf(acc[j][m][0]), f2bf(acc[j][m][1]),
                              f2bf(acc[j][m][2]), f2bf(acc[j][m][3]) };
                *(ushort4*)(T + w * 256 + ((((o0 >> 3) ^ (w & 7)) << 3) | (o0 & 7))) = u;
            }
        }
    }
    __syncthreads();

    // ---- stage 3: attn. A-op = KT rows x, B-op = QT rows w.
    //      D[row=x][col=w], acc in regs ----
    f32x4 acc3[2] = { { 0, 0, 0, 0 }, { 0, 0, 0, 0 } };
    const int wt3 = wv_ >> 1;          // w-tile 0..3
    const int xb3 = (wv_ & 1) * 2;     // x-tiles xb3, xb3+1
    {
        const int w = wt3 * 16 + l15;
        #pragma unroll
        for (int kk = 0; kk < 8; ++kk) {
            bf16x8 qf = *(const bf16x8*)(QT + w * 256 + (((kk * 4 + g) ^ (w & 7)) << 3));
            #pragma unroll
            for (int j = 0; j < 2; ++j) {
                int x = (xb3 + j) * 16 + l15;
                bf16x8 kf = *(const bf16x8*)(KT + x * 256 + (((kk * 4 + g) ^ (x & 7)) << 3));
                acc3[j] = __builtin_amdgcn_mfma_f32_16x16x32_bf16(kf, qf, acc3[j], 0, 0, 0);
            }
        }
    }
    __syncthreads();   // all QT/KT reads done; safe to overwrite with ATT/Vs

    // ---- ATT write (over KT region): lane col=w, regs = 4 consecutive x ----
    {
        const int w = wt3 * 16 + l15;
        #pragma unroll
        for (int j = 0; j < 2; ++j) {
            int x0 = (xb3 + j) * 16 + g * 4;
            ushort4 u = { f2bf(acc3[j][0]), f2bf(acc3[j][1]),
                          f2bf(acc3[j][2]), f2bf(acc3[j][3]) };
            *(ushort4*)(ATT + w * 64 + ((((x0 >> 3) ^ (w & 7)) << 3) | (x0 & 7))) = u;
        }
    }

    // ---- stage 2b: V proj. A-op = AT rows x, B-op = Wv rows c.
    //      D[row=x][col=c] -> ushort4 epilogue along x into Vs[c][x] ----
    {
        f32x4 acc[2][4];
        #pragma unroll
        for (int mi = 0; mi < 2; ++mi) {
            int c = (wv_ * 2 + mi) * 16 + l15;
            float bvl = bv[c];
            #pragma unroll
            for (int n = 0; n < 4; ++n) acc[mi][n] = { bvl, bvl, bvl, bvl };
        }
        #pragma unroll
        for (int kk = 0; kk < 8; ++kk) {
            bf16x8 wvf[2], atx[4];
            #pragma unroll
            for (int mi = 0; mi < 2; ++mi) {
                int c = (wv_ * 2 + mi) * 16 + l15;
                wvf[mi] = *(const bf16x8*)(wsb + 131072 + c * 256 + kk * 32 + g * 8);
            }
            #pragma unroll
            for (int n = 0; n < 4; ++n) {
                int x = n * 16 + l15;
                atx[n] = *(const bf16x8*)(AT + x * 256 + (((kk * 4 + g) ^ (x & 7)) << 3));
            }
            #pragma unroll
            for (int mi = 0; mi < 2; ++mi)
                #pragma unroll
                for (int n = 0; n < 4; ++n)
                    acc[mi][n] = __builtin_amdgcn_mfma_f32_16x16x32_bf16(atx[n], wvf[mi], acc[mi][n], 0, 0, 0);
        }
        #pragma unroll
        for (int mi = 0; mi < 2; ++mi) {
            int c = (wv_ * 2 + mi) * 16 + l15;
            #pragma unroll
            for (int n = 0; n < 4; ++n) {
                int x0 = n * 16 + g * 4;
                ushort4 u = { f2bf(acc[mi][n][0]), f2bf(acc[mi][n][1]),
                              f2bf(acc[mi][n][2]), f2bf(acc[mi][n][3]) };
                *(ushort4*)(Vs + c * 64 + ((((x0 >> 3) ^ (c & 7)) << 3) | (x0 & 7))) = u;
            }
        }
    }
    __syncthreads();

    // ---- stage 4: O = ATT x Vs. A-op = ATT rows w, B-op = Vs rows c.
    //      D[row=w][col=c] -> float4 residual epilogue along w ----
    {
        f32x4 acc[2][4];
        #pragma unroll
        for (int mi = 0; mi < 2; ++mi)
            #pragma unroll
            for (int n = 0; n < 4; ++n)
                acc[mi][n] = { 0.f, 0.f, 0.f, 0.f };
        #pragma unroll
        for (int kk = 0; kk < 2; ++kk) {
            bf16x8 attf[4], vsf[2];
            #pragma unroll
            for (int n = 0; n < 4; ++n) {
                int w = n * 16 + l15;
                attf[n] = *(const bf16x8*)(ATT + w * 64 + (((kk * 4 + g) ^ (w & 7)) << 3));
            }
            #pragma unroll
            for (int mi = 0; mi < 2; ++mi) {
                int c = (wv_ * 2 + mi) * 16 + l15;
                vsf[mi] = *(const bf16x8*)(Vs + c * 64 + (((kk * 4 + g) ^ (c & 7)) << 3));
            }
            #pragma unroll
            for (int mi = 0; mi < 2; ++mi)
                #pragma unroll
                for (int n = 0; n < 4; ++n)
                    acc[mi][n] = __builtin_amdgcn_mfma_f32_16x16x32_bf16(attf[n], vsf[mi], acc[mi][n], 0, 0, 0);
        }
        float* outB = out + (size_t)b * (NC * NH * NW) + h * NW;
        #pragma unroll
        for (int mi = 0; mi < 2; ++mi) {
            int c = (wv_ * 2 + mi) * 16 + l15;
            const float* ain = aB + (size_t)c * 4096;
            float* po = outB + (size_t)c * 4096;
            #pragma unroll
            for (int n = 0; n < 4; ++n) {
                int w0 = n * 16 + g * 4;
                float4 res = *(const float4*)(ain + w0);
                float4 o4;
                o4.x = res.x + acc[mi][n][0];
                o4.y = res.y + acc[mi][n][1];
                o4.z = res.z + acc[mi][n][2];
                o4.w = res.w + acc[mi][n][3];
                *(float4*)(po + w0) = o4;
            }
        }
    }
}

extern "C" void kernel_launch(void* const* d_in, const int* in_sizes, int n_in,
                              void* d_out, int out_size, void* d_ws, size_t ws_size,
                              hipStream_t stream) {
    (void)in_sizes; (void)n_in; (void)out_size; (void)ws_size;
    const float* a  = (const float*)d_in[0];
    const float* wq = (const float*)d_in[1];
    const float* bq = (const float*)d_in[2];
    const float* wk = (const float*)d_in[3];
    const float* bk = (const float*)d_in[4];
    const float* wv = (const float*)d_in[5];
    const float* bv = (const float*)d_in[6];
    float* out = (float*)d_out;
    unsigned short* wsb = (unsigned short*)d_ws;  // 3 x 256x256 bf16 weights

    conv_weights<<<dim3(64), dim3(256), 0, stream>>>(wq, wk, wv, wsb);
    mha_fused<<<dim3(NB * NH), dim3(512), 0, stream>>>(a, wsb, bq, bk, bv, out);
}